// Round 1
// baseline (1554.673 us; speedup 1.0000x reference)
//
#include <hip/hip_runtime.h>
#include <math.h>

#define GG   10000
#define NN0  32
#define EE0  64
#define NFF  64
#define HH   128
#define DD   256
#define BB   4096
#define E2B  8192
#define SIXH 768

// ============================================================
// Per-graph fused pipeline: GCN1 -> pool1 -> GCN2 -> pool2 -> GCN3 -> pool3
// One block (256 threads) per graph; everything in LDS.
// ============================================================

// out[M][128] = xT[K][M] @ W[K][128]   (W staged through LDS in 16-row chunks)
template<int M, int K>
__device__ __forceinline__ void matmul_x(const float* __restrict__ Wg,
                                         const float* s_xt, float* s_w,
                                         float* s_out, int t)
{
  constexpr int R = M / 8;           // rows per thread-group (4/2/1)
  const int ng = t >> 5;             // 8 node-groups
  const int f0 = (t & 31) * 4;       // 32 column-groups of 4
  float acc[R][4];
#pragma unroll
  for (int r = 0; r < R; ++r) { acc[r][0]=0.f; acc[r][1]=0.f; acc[r][2]=0.f; acc[r][3]=0.f; }
  for (int kc = 0; kc < K; kc += 16) {
    __syncthreads();
#pragma unroll
    for (int i = 0; i < 8; ++i) s_w[i*256 + t] = Wg[kc*HH + i*256 + t];
    __syncthreads();
#pragma unroll
    for (int k = 0; k < 16; ++k) {
      const float4 w = *(const float4*)(s_w + k*HH + f0);
#pragma unroll
      for (int r = 0; r < R; ++r) {
        const float a = s_xt[(kc + k)*32 + ng*R + r];   // broadcast across lanes
        acc[r][0] = fmaf(a, w.x, acc[r][0]);
        acc[r][1] = fmaf(a, w.y, acc[r][1]);
        acc[r][2] = fmaf(a, w.z, acc[r][2]);
        acc[r][3] = fmaf(a, w.w, acc[r][3]);
      }
    }
  }
#pragma unroll
  for (int r = 0; r < R; ++r) {
    float4 v; v.x=acc[r][0]; v.y=acc[r][1]; v.z=acc[r][2]; v.w=acc[r][3];
    *(float4*)(s_out + (ng*R + r)*HH + f0) = v;
  }
  __syncthreads();
}

// GCN normalization + aggregation + bias + relu (h already in s_a)
template<int M>
__device__ __forceinline__ void gcn_rest(float* s_a, float* s_b, float* s_dis, float* s_norm,
    const int* s_src, const int* s_dst, const float* s_ew,
    const float* __restrict__ bvec, int t)
{
  if (t < M) {
    float d = 1.f;
    for (int e = 0; e < EE0; ++e) d += (s_dst[e] == t) ? s_ew[e] : 0.f;
    s_dis[t] = rsqrtf(d);
  }
  __syncthreads();
  if (t < EE0) s_norm[t] = s_dis[s_src[t]] * s_ew[t] * s_dis[s_dst[t]];
  __syncthreads();
  if (t < HH) {   // each thread owns one feature column -> conflict-free scatter
#pragma unroll
    for (int n = 0; n < M; ++n) s_b[n*HH + t] = 0.f;
    for (int e = 0; e < EE0; ++e) s_b[s_dst[e]*HH + t] += s_norm[e] * s_a[s_src[e]*HH + t];
  }
  __syncthreads();
  for (int idx = t; idx < M*HH; idx += 256) {
    int n = idx >> 7, f = idx & 127;
    float di = s_dis[n];
    s_a[idx] = fmaxf(s_b[idx] + di*di*s_a[idx] + bvec[f], 0.f);
  }
  __syncthreads();
}

// SAGPool: score, rank (== jax.lax.top_k order, ties -> lower index),
// gate+compact to s_b, readout to feat, edge remap, transpose to s_xt.
template<int M, int KK, bool LAST>
__device__ __forceinline__ void sag_stage(const float* s_a, float* s_b, float* s_xt,
    float* s_score, int* s_rank, int* s_src, int* s_dst, float* s_ew,
    const float* __restrict__ Wr, const float* __restrict__ Wn, const float* __restrict__ bs,
    float* __restrict__ featg, int t)
{
  if (t < HH) {   // agg = scatter(ew * x[src]) -> dst
#pragma unroll
    for (int n = 0; n < M; ++n) s_b[n*HH + t] = 0.f;
    for (int e = 0; e < EE0; ++e) s_b[s_dst[e]*HH + t] += s_ew[e] * s_a[s_src[e]*HH + t];
  }
  __syncthreads();
  if (t < M) {    // score = tanh(agg@Wn + bn + x@Wr); rotated f to avoid bank conflicts
    float sc = bs[0];
    for (int ff = 0; ff < HH; ++ff) {
      int f = (ff + t) & (HH - 1);
      sc += s_b[t*HH + f]*Wn[f] + s_a[t*HH + f]*Wr[f];
    }
    s_score[t] = tanhf(sc);
  }
  __syncthreads();
  if (t < M) {
    float st = s_score[t]; int r = 0;
    for (int m = 0; m < M; ++m) {
      float sm = s_score[m];
      r += (sm > st) || (sm == st && m < t);
    }
    s_rank[t] = r;
  }
  __syncthreads();
  if (t < HH) {   // gate kept nodes by score, compact into rank order
#pragma unroll
    for (int n = 0; n < M; ++n) {
      int r = s_rank[n];
      if (r < KK) s_b[r*HH + t] = s_a[n*HH + t] * s_score[n];
    }
  }
  __syncthreads();
  if (t < HH) {   // readout: gmp || gap
    float mx = -INFINITY, sm = 0.f;
#pragma unroll
    for (int r = 0; r < KK; ++r) {
      float v = s_b[r*HH + t];
      mx = fmaxf(mx, v); sm += v;
    }
    featg[t] = mx;
    featg[HH + t] = sm * (1.f / KK);
  }
  if (!LAST) {
    if (t < EE0) {  // edge remap; filtered edges -> weight 0, node 0 (matches ref)
      int a = s_rank[s_src[t]];
      int b = s_rank[s_dst[t]];
      bool val = (a < KK) && (b < KK);
      s_ew[t]  = val ? s_ew[t] : 0.f;
      s_src[t] = val ? a : 0;
      s_dst[t] = val ? b : 0;
    }
    __syncthreads();
    for (int idx = t; idx < KK*HH; idx += 256) {   // transpose for next matmul
      int n = idx >> 7, k = idx & 127;
      s_xt[k*32 + n] = s_b[idx];
    }
  }
  __syncthreads();
}

__global__ __launch_bounds__(256, 2) void graph_kernel(
    const float* __restrict__ x,
    const int* __restrict__ esrc, const int* __restrict__ edst, const float* __restrict__ ewg,
    const float* __restrict__ W1, const float* __restrict__ b1,
    const float* __restrict__ Ws1r, const float* __restrict__ Ws1n, const float* __restrict__ bs1,
    const float* __restrict__ W2, const float* __restrict__ b2,
    const float* __restrict__ Ws2r, const float* __restrict__ Ws2n, const float* __restrict__ bs2,
    const float* __restrict__ W3, const float* __restrict__ b3,
    const float* __restrict__ Ws3r, const float* __restrict__ Ws3n, const float* __restrict__ bs3,
    float* __restrict__ feat)
{
  __shared__ __align__(16) float s_a[NN0*HH];   // node features / GCN output
  __shared__ __align__(16) float s_b[NN0*HH];   // aggregation scratch / gated features
  __shared__ __align__(16) float s_xt[HH*NN0];  // transposed matmul input [k][n]
  __shared__ __align__(16) float s_w[16*HH];    // weight chunk
  __shared__ float s_dis[NN0];
  __shared__ float s_score[NN0];
  __shared__ int   s_rank[NN0];
  __shared__ int   s_src[EE0], s_dst[EE0];
  __shared__ float s_ew[EE0], s_norm[EE0];

  const int t = threadIdx.x;
  const int g = blockIdx.x;

  // load x transposed: s_xt[k][n] = x[g*32+n][k], k<64
  for (int idx = t; idx < NN0*NFF; idx += 256) {
    int n = idx >> 6, k = idx & 63;
    s_xt[k*32 + n] = x[(size_t)(g*NN0 + n)*NFF + k];
  }
  if (t < EE0) {
    int e = g*EE0 + t;
    s_src[t] = esrc[e] - g*NN0;
    s_dst[t] = edst[e] - g*NN0;
    s_ew[t]  = ewg[e];
  }

  float* featg = feat + (size_t)g * SIXH;

  matmul_x<NN0, NFF>(W1, s_xt, s_w, s_a, t);
  gcn_rest<NN0>(s_a, s_b, s_dis, s_norm, s_src, s_dst, s_ew, b1, t);
  sag_stage<NN0, 16, false>(s_a, s_b, s_xt, s_score, s_rank, s_src, s_dst, s_ew,
                            Ws1r, Ws1n, bs1, featg + 0, t);

  matmul_x<16, HH>(W2, s_xt, s_w, s_a, t);
  gcn_rest<16>(s_a, s_b, s_dis, s_norm, s_src, s_dst, s_ew, b2, t);
  sag_stage<16, 8, false>(s_a, s_b, s_xt, s_score, s_rank, s_src, s_dst, s_ew,
                          Ws2r, Ws2n, bs2, featg + 256, t);

  matmul_x<8, HH>(W3, s_xt, s_w, s_a, t);
  gcn_rest<8>(s_a, s_b, s_dis, s_norm, s_src, s_dst, s_ew, b3, t);
  sag_stage<8, 4, true>(s_a, s_b, s_xt, s_score, s_rank, s_src, s_dst, s_ew,
                        Ws3r, Ws3n, bs3, featg + 512, t);
}

// ============================================================
// DDI stage
// ============================================================

__global__ void k_deg_init(float* __restrict__ degf) {
  int i = blockIdx.x*256 + threadIdx.x;
  if (i < GG) degf[i] = 1.f;
}

__global__ void k_deg_acc(const int* __restrict__ ddi, float* __restrict__ degf) {
  int e = blockIdx.x*256 + threadIdx.x;
  if (e < E2B) atomicAdd(&degf[ddi[E2B + e]], 1.f);
}

// hdd[G,256] = feat[G,768] @ Wd[768,256]
__global__ __launch_bounds__(256) void k_ddi_gemm(const float* __restrict__ feat,
    const float* __restrict__ Wd, float* __restrict__ hdd)
{
  __shared__ __align__(16) float s_f[32*257];
  const int t = threadIdx.x;
  const int r0 = blockIdx.x * 32;
  const int cg = t & 63, rg = t >> 6;   // 4 cols x 8 rows per thread
  float acc[8][4];
#pragma unroll
  for (int r = 0; r < 8; ++r) { acc[r][0]=0.f; acc[r][1]=0.f; acc[r][2]=0.f; acc[r][3]=0.f; }
  for (int kc = 0; kc < SIXH; kc += 256) {
    __syncthreads();
    for (int idx = t; idx < 32*256; idx += 256) {
      int r = idx >> 8, k = idx & 255;
      int row = r0 + r;
      s_f[r*257 + k] = (row < GG) ? feat[(size_t)row*SIXH + kc + k] : 0.f;
    }
    __syncthreads();
    for (int k = 0; k < 256; ++k) {
      const float4 w = *(const float4*)(Wd + (size_t)(kc + k)*DD + cg*4);
#pragma unroll
      for (int r = 0; r < 8; ++r) {
        float a = s_f[(rg*8 + r)*257 + k];   // broadcast within wave
        acc[r][0]=fmaf(a,w.x,acc[r][0]); acc[r][1]=fmaf(a,w.y,acc[r][1]);
        acc[r][2]=fmaf(a,w.z,acc[r][2]); acc[r][3]=fmaf(a,w.w,acc[r][3]);
      }
    }
  }
#pragma unroll
  for (int r = 0; r < 8; ++r) {
    int row = r0 + rg*8 + r;
    if (row < GG) {
      float4 v; v.x=acc[r][0]; v.y=acc[r][1]; v.z=acc[r][2]; v.w=acc[r][3];
      *(float4*)(hdd + (size_t)row*DD + cg*4) = v;
    }
  }
}

__global__ void k_z_init(const float* __restrict__ hdd, const float* __restrict__ degf,
                         const float* __restrict__ bd, float* __restrict__ z)
{
  int idx = blockIdx.x*256 + threadIdx.x;
  if (idx < GG*DD) {
    int g = idx >> 8, f = idx & 255;
    z[idx] = hdd[idx] / degf[g] + bd[f];   // self-loop term + bias
  }
}

__global__ void k_scatter(const int* __restrict__ ddi, const float* __restrict__ degf,
                          const float* __restrict__ hdd, float* __restrict__ z)
{
  int e = blockIdx.x; int t = threadIdx.x;
  int s = ddi[e], d = ddi[E2B + e];
  float nrm = rsqrtf(degf[s]) * rsqrtf(degf[d]);
  atomicAdd(&z[(size_t)d*DD + t], nrm * hdd[(size_t)s*DD + t]);
}

// link-prediction heads + row norms; 32 edges per block
__global__ __launch_bounds__(256) void k_final(const float* __restrict__ z,
    const int* __restrict__ ddi, const float* __restrict__ attr,
    const float* __restrict__ Wl1, const float* __restrict__ bl1,
    const float* __restrict__ Wl2, const float* __restrict__ bl2,
    const float* __restrict__ Wl3, const float* __restrict__ bl3,
    float* __restrict__ out)
{
  __shared__ __align__(16) float s_u[32*257];
  const int t = threadIdx.x;
  const int e0 = blockIdx.x * 32;
  float lacc[32], acc[32];

  // ---- X = sigmoid(relu(z[src]) @ Wl1 + bl1); write pos_x for e < B
  for (int idx = t; idx < 32*256; idx += 256) {
    int r = idx >> 8, k = idx & 255;
    int src = ddi[e0 + r];
    s_u[r*257 + k] = fmaxf(z[(size_t)src*DD + k], 0.f);
  }
  __syncthreads();
#pragma unroll
  for (int r = 0; r < 32; ++r) acc[r] = bl1[t];
  for (int k = 0; k < 256; ++k) {
    float w = Wl1[(size_t)k*DD + t];
#pragma unroll
    for (int r = 0; r < 32; ++r) acc[r] = fmaf(s_u[r*257 + k], w, acc[r]);
  }
#pragma unroll
  for (int r = 0; r < 32; ++r) {
    float sx = 1.f / (1.f + expf(-acc[r]));
    lacc[r] = sx;
    int e = e0 + r;
    if (e < BB) out[12288 + (size_t)e*DD + t] = sx;
  }
  __syncthreads();

  // ---- Y = sigmoid(relu(z[dst]) @ Wl2 + bl2)
  for (int idx = t; idx < 32*256; idx += 256) {
    int r = idx >> 8, k = idx & 255;
    int dst = ddi[E2B + e0 + r];
    s_u[r*257 + k] = fmaxf(z[(size_t)dst*DD + k], 0.f);
  }
  __syncthreads();
#pragma unroll
  for (int r = 0; r < 32; ++r) acc[r] = bl2[t];
  for (int k = 0; k < 256; ++k) {
    float w = Wl2[(size_t)k*DD + t];
#pragma unroll
    for (int r = 0; r < 32; ++r) acc[r] = fmaf(s_u[r*257 + k], w, acc[r]);
  }
#pragma unroll
  for (int r = 0; r < 32; ++r) lacc[r] -= 1.f / (1.f + expf(-acc[r]));
  __syncthreads();

  // ---- A = sigmoid(attr @ Wl3 + bl3)
  for (int idx = t; idx < 32*64; idx += 256) {
    int r = idx >> 6, k = idx & 63;
    s_u[r*257 + k] = attr[(size_t)(e0 + r)*NFF + k];
  }
  __syncthreads();
#pragma unroll
  for (int r = 0; r < 32; ++r) acc[r] = bl3[t];
  for (int k = 0; k < 64; ++k) {
    float w = Wl3[(size_t)k*DD + t];
#pragma unroll
    for (int r = 0; r < 32; ++r) acc[r] = fmaf(s_u[r*257 + k], w, acc[r]);
  }
#pragma unroll
  for (int r = 0; r < 32; ++r) lacc[r] += 1.f / (1.f + expf(-acc[r]));
  __syncthreads();

  // ---- squared residual, per-row reduce -> norms
#pragma unroll
  for (int r = 0; r < 32; ++r) s_u[r*257 + t] = lacc[r]*lacc[r];
  __syncthreads();
  if (t < 32) {
    float s = 0.f;
    for (int k = 0; k < 256; ++k) s += s_u[t*257 + k];
    float nrm = sqrtf(s);
    int e = e0 + t;
    if (e < BB) out[4096 + e] = nrm;
    else        out[8192 + (e - BB)] = nrm;
  }
}

__global__ void k_loss(float* __restrict__ out) {
  int i = blockIdx.x*256 + threadIdx.x;
  if (i < BB) out[i] = 2.f*(float)DD - out[4096 + i] + 0.5f*out[8192 + i];
}

// ============================================================

extern "C" void kernel_launch(void* const* d_in, const int* in_sizes, int n_in,
                              void* d_out, int out_size, void* d_ws, size_t ws_size,
                              hipStream_t stream)
{
  const float* x    = (const float*)d_in[0];
  const int*   esrc = (const int*)d_in[1];
  const int*   edst = (const int*)d_in[2];
  const float* ewt  = (const float*)d_in[3];
  const int*   ddi  = (const int*)d_in[4];
  const float* attr = (const float*)d_in[5];
  const float* W1   = (const float*)d_in[6];  const float* b1  = (const float*)d_in[7];
  const float* Ws1r = (const float*)d_in[8];  const float* Ws1n= (const float*)d_in[9];  const float* bs1 = (const float*)d_in[10];
  const float* W2   = (const float*)d_in[11]; const float* b2  = (const float*)d_in[12];
  const float* Ws2r = (const float*)d_in[13]; const float* Ws2n= (const float*)d_in[14]; const float* bs2 = (const float*)d_in[15];
  const float* W3   = (const float*)d_in[16]; const float* b3  = (const float*)d_in[17];
  const float* Ws3r = (const float*)d_in[18]; const float* Ws3n= (const float*)d_in[19]; const float* bs3 = (const float*)d_in[20];
  const float* Wd   = (const float*)d_in[21]; const float* bd  = (const float*)d_in[22];
  const float* Wl1  = (const float*)d_in[23]; const float* bl1 = (const float*)d_in[24];
  const float* Wl2  = (const float*)d_in[25]; const float* bl2 = (const float*)d_in[26];
  const float* Wl3  = (const float*)d_in[27]; const float* bl3 = (const float*)d_in[28];

  float* ws   = (float*)d_ws;
  float* feat = ws;                               // G*768 = 7,680,000 f32
  float* hdd  = feat + (size_t)GG*SIXH;           // G*256
  float* zb   = hdd  + (size_t)GG*DD;             // G*256
  float* degf = zb   + (size_t)GG*DD;             // G
  float* out  = (float*)d_out;

  graph_kernel<<<GG, 256, 0, stream>>>(x, esrc, edst, ewt,
      W1, b1, Ws1r, Ws1n, bs1, W2, b2, Ws2r, Ws2n, bs2, W3, b3, Ws3r, Ws3n, bs3, feat);
  k_deg_init<<<(GG + 255)/256, 256, 0, stream>>>(degf);
  k_deg_acc<<<(E2B + 255)/256, 256, 0, stream>>>(ddi, degf);
  k_ddi_gemm<<<(GG + 31)/32, 256, 0, stream>>>(feat, Wd, hdd);
  k_z_init<<<(GG*DD + 255)/256, 256, 0, stream>>>(hdd, degf, bd, zb);
  k_scatter<<<E2B, 256, 0, stream>>>(ddi, degf, hdd, zb);
  k_final<<<E2B/32, 256, 0, stream>>>(zb, ddi, attr, Wl1, bl1, Wl2, bl2, Wl3, bl3, out);
  k_loss<<<(BB + 255)/256, 256, 0, stream>>>(out);
}

// Round 2
// 929.886 us; speedup vs baseline: 1.6719x; 1.6719x over previous
//
#include <hip/hip_runtime.h>
#include <math.h>

#define GG   10000
#define NN0  32
#define EE0  64
#define NFF  64
#define HH   128
#define DD   256
#define BB   4096
#define E2B  8192
#define SIXH 768

// ============================================================
// Per-graph fused pipeline, dense-adjacency formulation.
// One block (256 threads) per graph. 38.5 KB LDS -> 4 blocks/CU.
// No atomics (bit-deterministic across graph replays).
// ============================================================

// bufH[i][f] = gate(i) * sum_k bufX[ind(i)][k] * W[k][f]
template<int M, int K, bool IND>
__device__ __forceinline__ void mm_xw(const float* __restrict__ Wg,
    const float* s_in, const int* s_inv, const float* s_score,
    float* s_out, int t)
{
  constexpr int R = M / 8;
  const int ng = t >> 5;
  const int f0 = (t & 31) * 4;
  int rs[R]; float gate[R];
#pragma unroll
  for (int r = 0; r < R; ++r) {
    int row = ng*R + r;
    rs[r] = IND ? s_inv[row] : row;
    gate[r] = IND ? s_score[rs[r]] : 1.f;
  }
  float acc[R][4];
#pragma unroll
  for (int r = 0; r < R; ++r) { acc[r][0]=0.f; acc[r][1]=0.f; acc[r][2]=0.f; acc[r][3]=0.f; }
#pragma unroll 8
  for (int k = 0; k < K; ++k) {
    const float4 w = *(const float4*)(Wg + (size_t)k*HH + f0);
#pragma unroll
    for (int r = 0; r < R; ++r) {
      const float a = s_in[rs[r]*HH + k];   // broadcast across 32 lanes
      acc[r][0]=fmaf(a,w.x,acc[r][0]); acc[r][1]=fmaf(a,w.y,acc[r][1]);
      acc[r][2]=fmaf(a,w.z,acc[r][2]); acc[r][3]=fmaf(a,w.w,acc[r][3]);
    }
  }
#pragma unroll
  for (int r = 0; r < R; ++r) {
    float4 v;
    if (IND) { v.x=acc[r][0]*gate[r]; v.y=acc[r][1]*gate[r]; v.z=acc[r][2]*gate[r]; v.w=acc[r][3]*gate[r]; }
    else     { v.x=acc[r][0]; v.y=acc[r][1]; v.z=acc[r][2]; v.w=acc[r][3]; }
    *(float4*)(s_out + (ng*R + r)*HH + f0) = v;
  }
}

// out[row] = relu(dis[row]*(sum_m A[row][m]*h'[m] + h'[row]) + b); fused
// v1[row] = out[row].Wn, v2[row] = out[row].Wr via 32-lane shuffle reduce.
template<int M>
__device__ __forceinline__ void gcn_mm(const float* s_h, const float* s_A, const float* s_dis,
    const float* __restrict__ bg, const float* __restrict__ Wn, const float* __restrict__ Wr,
    float* s_o, float* s_v1, float* s_v2, int t)
{
  constexpr int R = M / 8;
  const int ng = t >> 5;
  const int f0 = (t & 31) * 4;
  const float4 b4  = *(const float4*)(bg + f0);
  const float4 wn4 = *(const float4*)(Wn + f0);
  const float4 wr4 = *(const float4*)(Wr + f0);
  float acc[R][4];
#pragma unroll
  for (int r = 0; r < R; ++r) {     // seed with h'[row] == self-loop term
    const float4 h0 = *(const float4*)(s_h + (ng*R + r)*HH + f0);
    acc[r][0]=h0.x; acc[r][1]=h0.y; acc[r][2]=h0.z; acc[r][3]=h0.w;
  }
#pragma unroll 4
  for (int m = 0; m < M; ++m) {
    const float4 hm = *(const float4*)(s_h + m*HH + f0);
#pragma unroll
    for (int r = 0; r < R; ++r) {
      const float a = s_A[(ng*R + r)*33 + m];   // broadcast, pad-33 conflict-free
      acc[r][0]=fmaf(a,hm.x,acc[r][0]); acc[r][1]=fmaf(a,hm.y,acc[r][1]);
      acc[r][2]=fmaf(a,hm.z,acc[r][2]); acc[r][3]=fmaf(a,hm.w,acc[r][3]);
    }
  }
#pragma unroll
  for (int r = 0; r < R; ++r) {
    const int row = ng*R + r;
    const float dr = s_dis[row];
    float ox = fmaxf(fmaf(acc[r][0], dr, b4.x), 0.f);
    float oy = fmaxf(fmaf(acc[r][1], dr, b4.y), 0.f);
    float oz = fmaxf(fmaf(acc[r][2], dr, b4.z), 0.f);
    float ow = fmaxf(fmaf(acc[r][3], dr, b4.w), 0.f);
    float4 v; v.x=ox; v.y=oy; v.z=oz; v.w=ow;
    *(float4*)(s_o + row*HH + f0) = v;
    float p1 = ox*wn4.x + oy*wn4.y + oz*wn4.z + ow*wn4.w;
    float p2 = ox*wr4.x + oy*wr4.y + oz*wr4.z + ow*wr4.w;
#pragma unroll
    for (int off = 16; off >= 1; off >>= 1) {
      p1 += __shfl_xor(p1, off);
      p2 += __shfl_xor(p2, off);
    }
    if ((t & 31) == 0) { s_v1[row] = p1; s_v2[row] = p2; }
  }
}

template<int M, int KK, int K, bool IND, bool LAST>
__device__ __forceinline__ void stage(
    const float* __restrict__ Wg, const float* __restrict__ bg,
    const float* __restrict__ Wr, const float* __restrict__ Wn, const float* __restrict__ bs,
    float* bufX, float* bufH, float* s_A, float* s_dis,
    float* s_v1, float* s_v2, float* s_score, int* s_rank, int* s_inv,
    int* s_src, int* s_dst, float* s_ew,
    float* __restrict__ featg, int t)
{
  // A: h = gated/pooled x @ W
  mm_xw<M, K, IND>(Wg, bufX, s_inv, s_score, bufH, t);
  __syncthreads();
  // B: build raw A_w rows (deterministic, row-owner), deg -> dis
  if (t < M) {
#pragma unroll
    for (int m = 0; m < M; ++m) s_A[t*33 + m] = 0.f;
    for (int e = 0; e < EE0; ++e)
      if (s_dst[e] == t) s_A[t*33 + s_src[e]] += s_ew[e];
    float deg = 1.f;
    for (int m = 0; m < M; ++m) deg += s_A[t*33 + m];
    s_dis[t] = rsqrtf(deg);
  }
  __syncthreads();
  // B3: h' = dis * h
  for (int idx = t; idx < M*HH; idx += 256)
    bufH[idx] *= s_dis[idx >> 7];
  __syncthreads();
  // C: GCN out -> bufX (overwrites consumed x), fused v1/v2
  gcn_mm<M>(bufH, s_A, s_dis, bg, Wn, Wr, bufX, s_v1, s_v2, t);
  __syncthreads();
  // E: score = tanh(A_w @ v1 + v2 + bs)
  if (t < M) {
    float sc = bs[0] + s_v2[t];
    for (int m = 0; m < M; ++m) sc += s_A[t*33 + m] * s_v1[m];
    s_score[t] = tanhf(sc);
  }
  __syncthreads();
  // F: rank (jax.lax.top_k order, ties -> lower index) + inverse perm
  if (t < M) {
    float st = s_score[t]; int r = 0;
    for (int m = 0; m < M; ++m) {
      float sm = s_score[m];
      r += (sm > st) || (sm == st && m < t);
    }
    s_rank[t] = r;
    if (r < KK) s_inv[r] = t;
  }
  __syncthreads();
  // G2: readout (gmp || gap) over gated kept rows, read-through indirection
  {
    int f = t & 127, which = t >> 7;   // wave-uniform branch
    float acc = which ? 0.f : -INFINITY;
#pragma unroll
    for (int r = 0; r < KK; ++r) {
      int n = s_inv[r];
      float v = bufX[n*HH + f] * s_score[n];
      acc = which ? (acc + v) : fmaxf(acc, v);
    }
    featg[which*HH + f] = which ? acc * (1.f/KK) : acc;
  }
  // H: edge remap to compacted ids; filtered -> (0,0,w=0)
  if (!LAST && t < EE0) {
    int a = s_rank[s_src[t]], b = s_rank[s_dst[t]];
    bool val = (a < KK) && (b < KK);
    s_ew[t]  = val ? s_ew[t] : 0.f;
    s_src[t] = val ? a : 0;
    s_dst[t] = val ? b : 0;
  }
  __syncthreads();
}

__global__ __launch_bounds__(256, 4) void graph_kernel(
    const float* __restrict__ x,
    const int* __restrict__ esrc, const int* __restrict__ edst, const float* __restrict__ ewg,
    const float* __restrict__ W1, const float* __restrict__ b1,
    const float* __restrict__ Ws1r, const float* __restrict__ Ws1n, const float* __restrict__ bs1,
    const float* __restrict__ W2, const float* __restrict__ b2,
    const float* __restrict__ Ws2r, const float* __restrict__ Ws2n, const float* __restrict__ bs2,
    const float* __restrict__ W3, const float* __restrict__ b3,
    const float* __restrict__ Ws3r, const float* __restrict__ Ws3n, const float* __restrict__ bs3,
    float* __restrict__ feat)
{
  __shared__ __align__(16) float bufX[NN0*HH];
  __shared__ __align__(16) float bufH[NN0*HH];
  __shared__ float s_A[NN0*33];
  __shared__ float s_dis[NN0], s_v1[NN0], s_v2[NN0], s_score[NN0], s_ew[EE0];
  __shared__ int   s_rank[NN0], s_inv[NN0], s_src[EE0], s_dst[EE0];

  const int t = threadIdx.x;
  const int g = blockIdx.x;

  for (int idx = t; idx < NN0*NFF; idx += 256) {
    int n = idx >> 6, k = idx & 63;
    bufX[n*HH + k] = x[(size_t)g*NN0*NFF + idx];
  }
  if (t < EE0) {
    int e = g*EE0 + t;
    s_src[t] = esrc[e] - g*NN0;
    s_dst[t] = edst[e] - g*NN0;
    s_ew[t]  = ewg[e];
  }
  __syncthreads();

  float* featg = feat + (size_t)g * SIXH;

  stage<NN0, 16, NFF, false, false>(W1, b1, Ws1r, Ws1n, bs1,
      bufX, bufH, s_A, s_dis, s_v1, s_v2, s_score, s_rank, s_inv,
      s_src, s_dst, s_ew, featg, t);
  stage<16, 8, HH, true, false>(W2, b2, Ws2r, Ws2n, bs2,
      bufX, bufH, s_A, s_dis, s_v1, s_v2, s_score, s_rank, s_inv,
      s_src, s_dst, s_ew, featg + 256, t);
  stage<8, 4, HH, true, true>(W3, b3, Ws3r, Ws3n, bs3,
      bufX, bufH, s_A, s_dis, s_v1, s_v2, s_score, s_rank, s_inv,
      s_src, s_dst, s_ew, featg + 512, t);
}

// ============================================================
// DDI stage (unchanged this round)
// ============================================================

__global__ void k_deg_init(float* __restrict__ degf) {
  int i = blockIdx.x*256 + threadIdx.x;
  if (i < GG) degf[i] = 1.f;
}

__global__ void k_deg_acc(const int* __restrict__ ddi, float* __restrict__ degf) {
  int e = blockIdx.x*256 + threadIdx.x;
  if (e < E2B) atomicAdd(&degf[ddi[E2B + e]], 1.f);
}

__global__ __launch_bounds__(256) void k_ddi_gemm(const float* __restrict__ feat,
    const float* __restrict__ Wd, float* __restrict__ hdd)
{
  __shared__ __align__(16) float s_f[32*257];
  const int t = threadIdx.x;
  const int r0 = blockIdx.x * 32;
  const int cg = t & 63, rg = t >> 6;
  float acc[8][4];
#pragma unroll
  for (int r = 0; r < 8; ++r) { acc[r][0]=0.f; acc[r][1]=0.f; acc[r][2]=0.f; acc[r][3]=0.f; }
  for (int kc = 0; kc < SIXH; kc += 256) {
    __syncthreads();
    for (int idx = t; idx < 32*256; idx += 256) {
      int r = idx >> 8, k = idx & 255;
      int row = r0 + r;
      s_f[r*257 + k] = (row < GG) ? feat[(size_t)row*SIXH + kc + k] : 0.f;
    }
    __syncthreads();
    for (int k = 0; k < 256; ++k) {
      const float4 w = *(const float4*)(Wd + (size_t)(kc + k)*DD + cg*4);
#pragma unroll
      for (int r = 0; r < 8; ++r) {
        float a = s_f[(rg*8 + r)*257 + k];
        acc[r][0]=fmaf(a,w.x,acc[r][0]); acc[r][1]=fmaf(a,w.y,acc[r][1]);
        acc[r][2]=fmaf(a,w.z,acc[r][2]); acc[r][3]=fmaf(a,w.w,acc[r][3]);
      }
    }
  }
#pragma unroll
  for (int r = 0; r < 8; ++r) {
    int row = r0 + rg*8 + r;
    if (row < GG) {
      float4 v; v.x=acc[r][0]; v.y=acc[r][1]; v.z=acc[r][2]; v.w=acc[r][3];
      *(float4*)(hdd + (size_t)row*DD + cg*4) = v;
    }
  }
}

__global__ void k_z_init(const float* __restrict__ hdd, const float* __restrict__ degf,
                         const float* __restrict__ bd, float* __restrict__ z)
{
  int idx = blockIdx.x*256 + threadIdx.x;
  if (idx < GG*DD) {
    int g = idx >> 8, f = idx & 255;
    z[idx] = hdd[idx] / degf[g] + bd[f];
  }
}

__global__ void k_scatter(const int* __restrict__ ddi, const float* __restrict__ degf,
                          const float* __restrict__ hdd, float* __restrict__ z)
{
  int e = blockIdx.x; int t = threadIdx.x;
  int s = ddi[e], d = ddi[E2B + e];
  float nrm = rsqrtf(degf[s]) * rsqrtf(degf[d]);
  atomicAdd(&z[(size_t)d*DD + t], nrm * hdd[(size_t)s*DD + t]);
}

__global__ __launch_bounds__(256) void k_final(const float* __restrict__ z,
    const int* __restrict__ ddi, const float* __restrict__ attr,
    const float* __restrict__ Wl1, const float* __restrict__ bl1,
    const float* __restrict__ Wl2, const float* __restrict__ bl2,
    const float* __restrict__ Wl3, const float* __restrict__ bl3,
    float* __restrict__ out)
{
  __shared__ __align__(16) float s_u[32*257];
  const int t = threadIdx.x;
  const int e0 = blockIdx.x * 32;
  float lacc[32], acc[32];

  for (int idx = t; idx < 32*256; idx += 256) {
    int r = idx >> 8, k = idx & 255;
    int src = ddi[e0 + r];
    s_u[r*257 + k] = fmaxf(z[(size_t)src*DD + k], 0.f);
  }
  __syncthreads();
#pragma unroll
  for (int r = 0; r < 32; ++r) acc[r] = bl1[t];
  for (int k = 0; k < 256; ++k) {
    float w = Wl1[(size_t)k*DD + t];
#pragma unroll
    for (int r = 0; r < 32; ++r) acc[r] = fmaf(s_u[r*257 + k], w, acc[r]);
  }
#pragma unroll
  for (int r = 0; r < 32; ++r) {
    float sx = 1.f / (1.f + expf(-acc[r]));
    lacc[r] = sx;
    int e = e0 + r;
    if (e < BB) out[12288 + (size_t)e*DD + t] = sx;
  }
  __syncthreads();

  for (int idx = t; idx < 32*256; idx += 256) {
    int r = idx >> 8, k = idx & 255;
    int dst = ddi[E2B + e0 + r];
    s_u[r*257 + k] = fmaxf(z[(size_t)dst*DD + k], 0.f);
  }
  __syncthreads();
#pragma unroll
  for (int r = 0; r < 32; ++r) acc[r] = bl2[t];
  for (int k = 0; k < 256; ++k) {
    float w = Wl2[(size_t)k*DD + t];
#pragma unroll
    for (int r = 0; r < 32; ++r) acc[r] = fmaf(s_u[r*257 + k], w, acc[r]);
  }
#pragma unroll
  for (int r = 0; r < 32; ++r) lacc[r] -= 1.f / (1.f + expf(-acc[r]));
  __syncthreads();

  for (int idx = t; idx < 32*64; idx += 256) {
    int r = idx >> 6, k = idx & 63;
    s_u[r*257 + k] = attr[(size_t)(e0 + r)*NFF + k];
  }
  __syncthreads();
#pragma unroll
  for (int r = 0; r < 32; ++r) acc[r] = bl3[t];
  for (int k = 0; k < 64; ++k) {
    float w = Wl3[(size_t)k*DD + t];
#pragma unroll
    for (int r = 0; r < 32; ++r) acc[r] = fmaf(s_u[r*257 + k], w, acc[r]);
  }
#pragma unroll
  for (int r = 0; r < 32; ++r) lacc[r] += 1.f / (1.f + expf(-acc[r]));
  __syncthreads();

#pragma unroll
  for (int r = 0; r < 32; ++r) s_u[r*257 + t] = lacc[r]*lacc[r];
  __syncthreads();
  if (t < 32) {
    float s = 0.f;
    for (int k = 0; k < 256; ++k) s += s_u[t*257 + k];
    float nrm = sqrtf(s);
    int e = e0 + t;
    if (e < BB) out[4096 + e] = nrm;
    else        out[8192 + (e - BB)] = nrm;
  }
}

__global__ void k_loss(float* __restrict__ out) {
  int i = blockIdx.x*256 + threadIdx.x;
  if (i < BB) out[i] = 2.f*(float)DD - out[4096 + i] + 0.5f*out[8192 + i];
}

// ============================================================

extern "C" void kernel_launch(void* const* d_in, const int* in_sizes, int n_in,
                              void* d_out, int out_size, void* d_ws, size_t ws_size,
                              hipStream_t stream)
{
  const float* x    = (const float*)d_in[0];
  const int*   esrc = (const int*)d_in[1];
  const int*   edst = (const int*)d_in[2];
  const float* ewt  = (const float*)d_in[3];
  const int*   ddi  = (const int*)d_in[4];
  const float* attr = (const float*)d_in[5];
  const float* W1   = (const float*)d_in[6];  const float* b1  = (const float*)d_in[7];
  const float* Ws1r = (const float*)d_in[8];  const float* Ws1n= (const float*)d_in[9];  const float* bs1 = (const float*)d_in[10];
  const float* W2   = (const float*)d_in[11]; const float* b2  = (const float*)d_in[12];
  const float* Ws2r = (const float*)d_in[13]; const float* Ws2n= (const float*)d_in[14]; const float* bs2 = (const float*)d_in[15];
  const float* W3   = (const float*)d_in[16]; const float* b3  = (const float*)d_in[17];
  const float* Ws3r = (const float*)d_in[18]; const float* Ws3n= (const float*)d_in[19]; const float* bs3 = (const float*)d_in[20];
  const float* Wd   = (const float*)d_in[21]; const float* bd  = (const float*)d_in[22];
  const float* Wl1  = (const float*)d_in[23]; const float* bl1 = (const float*)d_in[24];
  const float* Wl2  = (const float*)d_in[25]; const float* bl2 = (const float*)d_in[26];
  const float* Wl3  = (const float*)d_in[27]; const float* bl3 = (const float*)d_in[28];

  float* ws   = (float*)d_ws;
  float* feat = ws;
  float* hdd  = feat + (size_t)GG*SIXH;
  float* zb   = hdd  + (size_t)GG*DD;
  float* degf = zb   + (size_t)GG*DD;
  float* out  = (float*)d_out;

  graph_kernel<<<GG, 256, 0, stream>>>(x, esrc, edst, ewt,
      W1, b1, Ws1r, Ws1n, bs1, W2, b2, Ws2r, Ws2n, bs2, W3, b3, Ws3r, Ws3n, bs3, feat);
  k_deg_init<<<(GG + 255)/256, 256, 0, stream>>>(degf);
  k_deg_acc<<<(E2B + 255)/256, 256, 0, stream>>>(ddi, degf);
  k_ddi_gemm<<<(GG + 31)/32, 256, 0, stream>>>(feat, Wd, hdd);
  k_z_init<<<(GG*DD + 255)/256, 256, 0, stream>>>(hdd, degf, bd, zb);
  k_scatter<<<E2B, 256, 0, stream>>>(ddi, degf, hdd, zb);
  k_final<<<E2B/32, 256, 0, stream>>>(zb, ddi, attr, Wl1, bl1, Wl2, bl2, Wl3, bl3, out);
  k_loss<<<(BB + 255)/256, 256, 0, stream>>>(out);
}

// Round 3
// 703.211 us; speedup vs baseline: 2.2108x; 1.3223x over previous
//
#include <hip/hip_runtime.h>
#include <math.h>

#define GG   10000
#define NN0  32
#define EE0  64
#define NFF  64
#define HH   128
#define DD   256
#define BB   4096
#define E2B  8192
#define SIXH 768
#define APAD 36

// ============================================================
// Per-graph fused pipeline, aggregate-first formulation:
//   out = relu((B @ x̂) @ W + b),  B = D·A·D·g + D²·g  (applied on the fly)
// One block (256 threads) per graph; ~31 KB LDS -> 5 blocks/CU.
// ============================================================

template<int M, int KK, int K, int SX, bool IND, bool LAST>
__device__ __forceinline__ void stage(
    const float* __restrict__ Wg, const float* __restrict__ bg,
    const float* __restrict__ Wr, const float* __restrict__ Wn, const float* __restrict__ bs,
    float* bufX, float* bufY, float* s_A,
    float* s_dis, float* s_cm, float* s_sc2,
    float* s_v1, float* s_v2, float* s_score, int* s_rank, int* s_inv,
    int* s_src, int* s_dst, float* s_ew,
    float* __restrict__ featg, int t)
{
  // P0: build raw A[dst][src] — one thread per 4 slots, register scan (no RMW chains)
  constexpr int TA = M*M/4;
  if (t < TA) {
    const int i  = t / (M/4);
    const int j0 = (t % (M/4)) * 4;
    float a0=0.f, a1=0.f, a2=0.f, a3=0.f;
    for (int e = 0; e < EE0; ++e) {
      const int d = s_dst[e], s = s_src[e];
      const float w = s_ew[e];
      if (d == i) {
        a0 += (s==j0  ) ? w : 0.f;
        a1 += (s==j0+1) ? w : 0.f;
        a2 += (s==j0+2) ? w : 0.f;
        a3 += (s==j0+3) ? w : 0.f;
      }
    }
    float4 v; v.x=a0; v.y=a1; v.z=a2; v.w=a3;
    *(float4*)(s_A + i*APAD + j0) = v;
  }
  __syncthreads();
  // P1: deg -> dis; cm[m] = dis_m*g_m; sc2[r] = dis_r^2*g_r
  if (t < M) {
    float deg = 1.f;
    for (int m = 0; m < M; ++m) deg += s_A[t*APAD + m];
    const float dis = rsqrtf(deg);
    const float g = IND ? s_score[s_inv[t]] : 1.f;
    s_dis[t] = dis;
    s_cm[t]  = dis * g;
    s_sc2[t] = dis * dis * g;
  }
  __syncthreads();
  // P2: y[r] = dis_r * sum_m A[r,m]*cm[m]*x[ind(m)] + sc2[r]*x[ind(r)]
  {
    constexpr int CGB = K/4, RGB = 256/CGB, R = M/RGB;
    const int cg = t % CGB, rg = t / CGB;
    const int c0 = cg * 4;
    float acc[R][4];
#pragma unroll
    for (int i = 0; i < R; ++i) { acc[i][0]=0.f; acc[i][1]=0.f; acc[i][2]=0.f; acc[i][3]=0.f; }
#pragma unroll 2
    for (int m0 = 0; m0 < M; m0 += 4) {
      float4 a[R];
#pragma unroll
      for (int i = 0; i < R; ++i)
        a[i] = *(const float4*)(s_A + (rg*R + i)*APAD + m0);
#pragma unroll
      for (int j = 0; j < 4; ++j) {
        const int m = m0 + j;
        const int row = IND ? s_inv[m] : m;
        const float4 xv = *(const float4*)(bufX + row*SX + c0);
        const float cmm = s_cm[m];
#pragma unroll
        for (int i = 0; i < R; ++i) {
          const float aj = (j==0) ? a[i].x : (j==1) ? a[i].y : (j==2) ? a[i].z : a[i].w;
          const float cf = aj * cmm;
          acc[i][0] = fmaf(cf, xv.x, acc[i][0]);
          acc[i][1] = fmaf(cf, xv.y, acc[i][1]);
          acc[i][2] = fmaf(cf, xv.z, acc[i][2]);
          acc[i][3] = fmaf(cf, xv.w, acc[i][3]);
        }
      }
    }
#pragma unroll
    for (int i = 0; i < R; ++i) {
      const int r = rg*R + i;
      const int rr = IND ? s_inv[r] : r;
      const float4 xv = *(const float4*)(bufX + rr*SX + c0);
      const float dr = s_dis[r], sc = s_sc2[r];
      float4 v;
      v.x = fmaf(sc, xv.x, acc[i][0]*dr);
      v.y = fmaf(sc, xv.y, acc[i][1]*dr);
      v.z = fmaf(sc, xv.z, acc[i][2]*dr);
      v.w = fmaf(sc, xv.w, acc[i][3]*dr);
      *(float4*)(bufY + r*K + c0) = v;
    }
  }
  __syncthreads();
  // P3: out = relu(y @ W + b) -> bufX; fused v1 = out.Wn, v2 = out.Wr
  {
    constexpr int R = M / 8;
    const int cg = t & 31, ng = t >> 5;
    const int f0 = cg * 4;
    const float4 b4  = *(const float4*)(bg + f0);
    const float4 wn4 = *(const float4*)(Wn + f0);
    const float4 wr4 = *(const float4*)(Wr + f0);
    float acc[R][4];
#pragma unroll
    for (int i = 0; i < R; ++i) { acc[i][0]=0.f; acc[i][1]=0.f; acc[i][2]=0.f; acc[i][3]=0.f; }
#pragma unroll 2
    for (int k0 = 0; k0 < K; k0 += 4) {
      const float4 w0 = *(const float4*)(Wg + (size_t)(k0+0)*HH + f0);
      const float4 w1 = *(const float4*)(Wg + (size_t)(k0+1)*HH + f0);
      const float4 w2 = *(const float4*)(Wg + (size_t)(k0+2)*HH + f0);
      const float4 w3 = *(const float4*)(Wg + (size_t)(k0+3)*HH + f0);
#pragma unroll
      for (int i = 0; i < R; ++i) {
        const float4 yv = *(const float4*)(bufY + (ng*R + i)*K + k0);
        acc[i][0]=fmaf(yv.x,w0.x,acc[i][0]); acc[i][1]=fmaf(yv.x,w0.y,acc[i][1]);
        acc[i][2]=fmaf(yv.x,w0.z,acc[i][2]); acc[i][3]=fmaf(yv.x,w0.w,acc[i][3]);
        acc[i][0]=fmaf(yv.y,w1.x,acc[i][0]); acc[i][1]=fmaf(yv.y,w1.y,acc[i][1]);
        acc[i][2]=fmaf(yv.y,w1.z,acc[i][2]); acc[i][3]=fmaf(yv.y,w1.w,acc[i][3]);
        acc[i][0]=fmaf(yv.z,w2.x,acc[i][0]); acc[i][1]=fmaf(yv.z,w2.y,acc[i][1]);
        acc[i][2]=fmaf(yv.z,w2.z,acc[i][2]); acc[i][3]=fmaf(yv.z,w2.w,acc[i][3]);
        acc[i][0]=fmaf(yv.w,w3.x,acc[i][0]); acc[i][1]=fmaf(yv.w,w3.y,acc[i][1]);
        acc[i][2]=fmaf(yv.w,w3.z,acc[i][2]); acc[i][3]=fmaf(yv.w,w3.w,acc[i][3]);
      }
    }
#pragma unroll
    for (int i = 0; i < R; ++i) {
      const int row = ng*R + i;
      const float ox = fmaxf(acc[i][0] + b4.x, 0.f);
      const float oy = fmaxf(acc[i][1] + b4.y, 0.f);
      const float oz = fmaxf(acc[i][2] + b4.z, 0.f);
      const float ow = fmaxf(acc[i][3] + b4.w, 0.f);
      float4 v; v.x=ox; v.y=oy; v.z=oz; v.w=ow;
      *(float4*)(bufX + row*HH + f0) = v;
      float p1 = ox*wn4.x + oy*wn4.y + oz*wn4.z + ow*wn4.w;
      float p2 = ox*wr4.x + oy*wr4.y + oz*wr4.z + ow*wr4.w;
#pragma unroll
      for (int off = 16; off >= 1; off >>= 1) {
        p1 += __shfl_xor(p1, off);
        p2 += __shfl_xor(p2, off);
      }
      if ((t & 31) == 0) { s_v1[row] = p1; s_v2[row] = p2; }
    }
  }
  __syncthreads();
  // P4: score = tanh(A_raw @ v1 + v2 + bs)
  if (t < M) {
    float sc = bs[0] + s_v2[t];
    for (int m = 0; m < M; ++m) sc += s_A[t*APAD + m] * s_v1[m];
    s_score[t] = tanhf(sc);
  }
  __syncthreads();
  // P5: rank (jax.lax.top_k order, ties -> lower index) + inverse perm
  if (t < M) {
    const float st = s_score[t]; int r = 0;
    for (int m = 0; m < M; ++m) {
      const float sm = s_score[m];
      r += (sm > st) || (sm == st && m < t);
    }
    s_rank[t] = r;
    if (r < KK) s_inv[r] = t;
  }
  __syncthreads();
  // P6: readout (gmp || gap) over gated kept rows; edge remap
  {
    const int f = t & 127, which = t >> 7;
    float acc = which ? 0.f : -INFINITY;
#pragma unroll
    for (int r = 0; r < KK; ++r) {
      const int n = s_inv[r];
      const float v = bufX[n*HH + f] * s_score[n];
      acc = which ? (acc + v) : fmaxf(acc, v);
    }
    featg[which*HH + f] = which ? acc * (1.f/KK) : acc;
  }
  if (!LAST && t < EE0) {
    const int a = s_rank[s_src[t]], b = s_rank[s_dst[t]];
    const bool val = (a < KK) && (b < KK);
    s_ew[t]  = val ? s_ew[t] : 0.f;
    s_src[t] = val ? a : 0;
    s_dst[t] = val ? b : 0;
  }
  __syncthreads();
}

__global__ __launch_bounds__(256, 5) void graph_kernel(
    const float* __restrict__ x,
    const int* __restrict__ esrc, const int* __restrict__ edst, const float* __restrict__ ewg,
    const float* __restrict__ W1, const float* __restrict__ b1,
    const float* __restrict__ Ws1r, const float* __restrict__ Ws1n, const float* __restrict__ bs1,
    const float* __restrict__ W2, const float* __restrict__ b2,
    const float* __restrict__ Ws2r, const float* __restrict__ Ws2n, const float* __restrict__ bs2,
    const float* __restrict__ W3, const float* __restrict__ b3,
    const float* __restrict__ Ws3r, const float* __restrict__ Ws3n, const float* __restrict__ bs3,
    float* __restrict__ feat)
{
  __shared__ __align__(16) float bufX[NN0*HH];   // x (stride 64) then GCN out (stride 128)
  __shared__ __align__(16) float bufY[2048];     // y = B@x̂ (stride K)
  __shared__ __align__(16) float s_A[NN0*APAD];  // raw adjacency
  __shared__ float s_dis[NN0], s_cm[NN0], s_sc2[NN0];
  __shared__ float s_v1[NN0], s_v2[NN0], s_score[NN0], s_ew[EE0];
  __shared__ int   s_rank[NN0], s_inv[NN0], s_src[EE0], s_dst[EE0];

  const int t = threadIdx.x;
  const int g = blockIdx.x;

  for (int idx = t; idx < NN0*NFF; idx += 256)
    bufX[idx] = x[(size_t)g*NN0*NFF + idx];     // packed stride 64
  if (t < EE0) {
    const int e = g*EE0 + t;
    s_src[t] = esrc[e] - g*NN0;
    s_dst[t] = edst[e] - g*NN0;
    s_ew[t]  = ewg[e];
  }
  __syncthreads();

  float* featg = feat + (size_t)g * SIXH;

  stage<NN0, 16, NFF, NFF, false, false>(W1, b1, Ws1r, Ws1n, bs1,
      bufX, bufY, s_A, s_dis, s_cm, s_sc2, s_v1, s_v2, s_score, s_rank, s_inv,
      s_src, s_dst, s_ew, featg, t);
  stage<16, 8, HH, HH, true, false>(W2, b2, Ws2r, Ws2n, bs2,
      bufX, bufY, s_A, s_dis, s_cm, s_sc2, s_v1, s_v2, s_score, s_rank, s_inv,
      s_src, s_dst, s_ew, featg + 256, t);
  stage<8, 4, HH, HH, true, true>(W3, b3, Ws3r, Ws3n, bs3,
      bufX, bufY, s_A, s_dis, s_cm, s_sc2, s_v1, s_v2, s_score, s_rank, s_inv,
      s_src, s_dst, s_ew, featg + 512, t);
}

// ============================================================
// DDI stage
// ============================================================

__global__ void k_deg_init(float* __restrict__ degf) {
  int i = blockIdx.x*256 + threadIdx.x;
  if (i < GG) degf[i] = 1.f;
}

__global__ void k_deg_acc(const int* __restrict__ ddi, float* __restrict__ degf) {
  int e = blockIdx.x*256 + threadIdx.x;
  if (e < E2B) atomicAdd(&degf[ddi[E2B + e]], 1.f);
}

// hdd[G,256] = feat[G,768] @ Wd[768,256]; 8 rows/block -> 1250 blocks
__global__ __launch_bounds__(256) void k_ddi_gemm(const float* __restrict__ feat,
    const float* __restrict__ Wd, float* __restrict__ hdd)
{
  __shared__ __align__(16) float s_f[8*SIXH];
  const int t = threadIdx.x;
  const int r0 = blockIdx.x * 8;
  const int cg = t & 63, rg = t >> 6;    // 4 cols x 2 rows per thread
  for (int idx = t; idx < 8*SIXH; idx += 256)
    s_f[idx] = feat[(size_t)r0*SIXH + idx];
  __syncthreads();
  float acc[2][4];
#pragma unroll
  for (int i = 0; i < 2; ++i) { acc[i][0]=0.f; acc[i][1]=0.f; acc[i][2]=0.f; acc[i][3]=0.f; }
#pragma unroll 4
  for (int k = 0; k < SIXH; ++k) {
    const float4 w = *(const float4*)(Wd + (size_t)k*DD + cg*4);
#pragma unroll
    for (int i = 0; i < 2; ++i) {
      const float a = s_f[(rg*2 + i)*SIXH + k];   // broadcast
      acc[i][0]=fmaf(a,w.x,acc[i][0]); acc[i][1]=fmaf(a,w.y,acc[i][1]);
      acc[i][2]=fmaf(a,w.z,acc[i][2]); acc[i][3]=fmaf(a,w.w,acc[i][3]);
    }
  }
#pragma unroll
  for (int i = 0; i < 2; ++i) {
    float4 v; v.x=acc[i][0]; v.y=acc[i][1]; v.z=acc[i][2]; v.w=acc[i][3];
    *(float4*)(hdd + (size_t)(r0 + rg*2 + i)*DD + cg*4) = v;
  }
}

__global__ void k_z_init(const float* __restrict__ hdd, const float* __restrict__ degf,
                         const float* __restrict__ bd, float* __restrict__ z)
{
  int idx = blockIdx.x*256 + threadIdx.x;
  if (idx < GG*DD) {
    int g = idx >> 8, f = idx & 255;
    z[idx] = hdd[idx] / degf[g] + bd[f];
  }
}

// 4 edges per block
__global__ void k_scatter(const int* __restrict__ ddi, const float* __restrict__ degf,
                          const float* __restrict__ hdd, float* __restrict__ z)
{
  const int t = threadIdx.x;
#pragma unroll
  for (int j = 0; j < 4; ++j) {
    const int e = blockIdx.x*4 + j;
    const int s = ddi[e], d = ddi[E2B + e];
    const float nrm = rsqrtf(degf[s]) * rsqrtf(degf[d]);
    atomicAdd(&z[(size_t)d*DD + t], nrm * hdd[(size_t)s*DD + t]);
  }
}

// link-prediction heads + row norms; 8 edges per block -> 1024 blocks
__global__ __launch_bounds__(256) void k_final(const float* __restrict__ z,
    const int* __restrict__ ddi, const float* __restrict__ attr,
    const float* __restrict__ Wl1, const float* __restrict__ bl1,
    const float* __restrict__ Wl2, const float* __restrict__ bl2,
    const float* __restrict__ Wl3, const float* __restrict__ bl3,
    float* __restrict__ out)
{
  __shared__ __align__(16) float s_u[8*257];
  const int t = threadIdx.x;
  const int e0 = blockIdx.x * 8;
  float lacc[8], acc[8];

  // ---- X = sigmoid(relu(z[src]) @ Wl1 + bl1)
  for (int idx = t; idx < 8*256; idx += 256) {
    const int r = idx >> 8, k = idx & 255;
    const int src = ddi[e0 + r];
    s_u[r*257 + k] = fmaxf(z[(size_t)src*DD + k], 0.f);
  }
  __syncthreads();
#pragma unroll
  for (int r = 0; r < 8; ++r) acc[r] = bl1[t];
#pragma unroll 4
  for (int k = 0; k < 256; ++k) {
    const float w = Wl1[(size_t)k*DD + t];
#pragma unroll
    for (int r = 0; r < 8; ++r) acc[r] = fmaf(s_u[r*257 + k], w, acc[r]);
  }
#pragma unroll
  for (int r = 0; r < 8; ++r) {
    const float sx = 1.f / (1.f + expf(-acc[r]));
    lacc[r] = sx;
    const int e = e0 + r;
    if (e < BB) out[12288 + (size_t)e*DD + t] = sx;
  }
  __syncthreads();

  // ---- Y = sigmoid(relu(z[dst]) @ Wl2 + bl2)
  for (int idx = t; idx < 8*256; idx += 256) {
    const int r = idx >> 8, k = idx & 255;
    const int dst = ddi[E2B + e0 + r];
    s_u[r*257 + k] = fmaxf(z[(size_t)dst*DD + k], 0.f);
  }
  __syncthreads();
#pragma unroll
  for (int r = 0; r < 8; ++r) acc[r] = bl2[t];
#pragma unroll 4
  for (int k = 0; k < 256; ++k) {
    const float w = Wl2[(size_t)k*DD + t];
#pragma unroll
    for (int r = 0; r < 8; ++r) acc[r] = fmaf(s_u[r*257 + k], w, acc[r]);
  }
#pragma unroll
  for (int r = 0; r < 8; ++r) lacc[r] -= 1.f / (1.f + expf(-acc[r]));
  __syncthreads();

  // ---- A = sigmoid(attr @ Wl3 + bl3)
  for (int idx = t; idx < 8*64; idx += 256) {
    const int r = idx >> 6, k = idx & 63;
    s_u[r*257 + k] = attr[(size_t)(e0 + r)*NFF + k];
  }
  __syncthreads();
#pragma unroll
  for (int r = 0; r < 8; ++r) acc[r] = bl3[t];
#pragma unroll 4
  for (int k = 0; k < 64; ++k) {
    const float w = Wl3[(size_t)k*DD + t];
#pragma unroll
    for (int r = 0; r < 8; ++r) acc[r] = fmaf(s_u[r*257 + k], w, acc[r]);
  }
#pragma unroll
  for (int r = 0; r < 8; ++r) lacc[r] += 1.f / (1.f + expf(-acc[r]));
  __syncthreads();

  // ---- squared residual, 32-lane row reduce
#pragma unroll
  for (int r = 0; r < 8; ++r) s_u[r*257 + t] = lacc[r]*lacc[r];
  __syncthreads();
  {
    const int row = t >> 5, l = t & 31;
    float s = 0.f;
#pragma unroll
    for (int j = 0; j < 8; ++j) s += s_u[row*257 + l + 32*j];
#pragma unroll
    for (int off = 16; off >= 1; off >>= 1) s += __shfl_xor(s, off);
    if (l == 0) {
      const float nrm = sqrtf(s);
      const int e = e0 + row;
      if (e < BB) out[4096 + e] = nrm;
      else        out[8192 + (e - BB)] = nrm;
    }
  }
}

__global__ void k_loss(float* __restrict__ out) {
  int i = blockIdx.x*256 + threadIdx.x;
  if (i < BB) out[i] = 2.f*(float)DD - out[4096 + i] + 0.5f*out[8192 + i];
}

// ============================================================

extern "C" void kernel_launch(void* const* d_in, const int* in_sizes, int n_in,
                              void* d_out, int out_size, void* d_ws, size_t ws_size,
                              hipStream_t stream)
{
  const float* x    = (const float*)d_in[0];
  const int*   esrc = (const int*)d_in[1];
  const int*   edst = (const int*)d_in[2];
  const float* ewt  = (const float*)d_in[3];
  const int*   ddi  = (const int*)d_in[4];
  const float* attr = (const float*)d_in[5];
  const float* W1   = (const float*)d_in[6];  const float* b1  = (const float*)d_in[7];
  const float* Ws1r = (const float*)d_in[8];  const float* Ws1n= (const float*)d_in[9];  const float* bs1 = (const float*)d_in[10];
  const float* W2   = (const float*)d_in[11]; const float* b2  = (const float*)d_in[12];
  const float* Ws2r = (const float*)d_in[13]; const float* Ws2n= (const float*)d_in[14]; const float* bs2 = (const float*)d_in[15];
  const float* W3   = (const float*)d_in[16]; const float* b3  = (const float*)d_in[17];
  const float* Ws3r = (const float*)d_in[18]; const float* Ws3n= (const float*)d_in[19]; const float* bs3 = (const float*)d_in[20];
  const float* Wd   = (const float*)d_in[21]; const float* bd  = (const float*)d_in[22];
  const float* Wl1  = (const float*)d_in[23]; const float* bl1 = (const float*)d_in[24];
  const float* Wl2  = (const float*)d_in[25]; const float* bl2 = (const float*)d_in[26];
  const float* Wl3  = (const float*)d_in[27]; const float* bl3 = (const float*)d_in[28];

  float* ws   = (float*)d_ws;
  float* feat = ws;
  float* hdd  = feat + (size_t)GG*SIXH;
  float* zb   = hdd  + (size_t)GG*DD;
  float* degf = zb   + (size_t)GG*DD;
  float* out  = (float*)d_out;

  graph_kernel<<<GG, 256, 0, stream>>>(x, esrc, edst, ewt,
      W1, b1, Ws1r, Ws1n, bs1, W2, b2, Ws2r, Ws2n, bs2, W3, b3, Ws3r, Ws3n, bs3, feat);
  k_deg_init<<<(GG + 255)/256, 256, 0, stream>>>(degf);
  k_deg_acc<<<(E2B + 255)/256, 256, 0, stream>>>(ddi, degf);
  k_ddi_gemm<<<GG/8, 256, 0, stream>>>(feat, Wd, hdd);
  k_z_init<<<(GG*DD + 255)/256, 256, 0, stream>>>(hdd, degf, bd, zb);
  k_scatter<<<E2B/4, 256, 0, stream>>>(ddi, degf, hdd, zb);
  k_final<<<E2B/8, 256, 0, stream>>>(zb, ddi, attr, Wl1, bl1, Wl2, bl2, Wl3, bl3, out);
  k_loss<<<(BB + 255)/256, 256, 0, stream>>>(out);
}

// Round 4
// 650.120 us; speedup vs baseline: 2.3914x; 1.0817x over previous
//
#include <hip/hip_runtime.h>
#include <math.h>

#define GG   10000
#define NN0  32
#define EE0  64
#define NFF  64
#define HH   128
#define DD   256
#define BB   4096
#define E2B  8192
#define SIXH 768
#define APAD 36

// ============================================================
// Per-graph fused pipeline, aggregate-first formulation:
//   out = relu((B @ x̂) @ W + b),  B = D·A·D·g + D²·g
// One block (256 threads) per graph; ~31 KB LDS -> 5 blocks/CU.
// P3 uses duplicate-free W loads (float2 per lane) and k-split
// across wave-pairs for K=128 stages to cut L1 W-traffic.
// ============================================================

template<int M, int KK, int K, int SX, bool IND, bool LAST>
__device__ __forceinline__ void stage(
    const float* __restrict__ Wg, const float* __restrict__ bg,
    const float* __restrict__ Wr, const float* __restrict__ Wn, const float* __restrict__ bs,
    float* bufX, float* bufY, float* s_A,
    float* s_dis, float* s_cm, float* s_sc2,
    float* s_v1, float* s_v2, float* s_score, int* s_rank, int* s_inv,
    int* s_src, int* s_dst, float* s_ew,
    float* __restrict__ featg, int t)
{
  // P0: build raw A[dst][src] — one thread per 4 slots, register scan
  constexpr int TA = M*M/4;
  if (t < TA) {
    const int i  = t / (M/4);
    const int j0 = (t % (M/4)) * 4;
    float a0=0.f, a1=0.f, a2=0.f, a3=0.f;
#pragma unroll 8
    for (int e = 0; e < EE0; ++e) {
      const int d = s_dst[e], s = s_src[e];
      const float w = s_ew[e];
      if (d == i) {
        a0 += (s==j0  ) ? w : 0.f;
        a1 += (s==j0+1) ? w : 0.f;
        a2 += (s==j0+2) ? w : 0.f;
        a3 += (s==j0+3) ? w : 0.f;
      }
    }
    float4 v; v.x=a0; v.y=a1; v.z=a2; v.w=a3;
    *(float4*)(s_A + i*APAD + j0) = v;
  }
  __syncthreads();
  // P1: deg -> dis; cm[m] = dis_m*g_m; sc2[r] = dis_r^2*g_r
  if (t < M) {
    float deg = 1.f;
    for (int m = 0; m < M; ++m) deg += s_A[t*APAD + m];
    const float dis = rsqrtf(deg);
    const float g = IND ? s_score[s_inv[t]] : 1.f;
    s_dis[t] = dis;
    s_cm[t]  = dis * g;
    s_sc2[t] = dis * dis * g;
  }
  __syncthreads();
  // P2: y[r] = dis_r * sum_m A[r,m]*cm[m]*x[ind(m)] + sc2[r]*x[ind(r)]
  {
    constexpr int CGB = K/4, RGB = 256/CGB, R = M/RGB;
    const int cg = t % CGB, rg = t / CGB;
    const int c0 = cg * 4;
    float acc[R][4];
#pragma unroll
    for (int i = 0; i < R; ++i) { acc[i][0]=0.f; acc[i][1]=0.f; acc[i][2]=0.f; acc[i][3]=0.f; }
#pragma unroll 2
    for (int m0 = 0; m0 < M; m0 += 4) {
      float4 a[R];
#pragma unroll
      for (int i = 0; i < R; ++i)
        a[i] = *(const float4*)(s_A + (rg*R + i)*APAD + m0);
#pragma unroll
      for (int j = 0; j < 4; ++j) {
        const int m = m0 + j;
        const int row = IND ? s_inv[m] : m;
        const float4 xv = *(const float4*)(bufX + row*SX + c0);
        const float cmm = s_cm[m];
#pragma unroll
        for (int i = 0; i < R; ++i) {
          const float aj = (j==0) ? a[i].x : (j==1) ? a[i].y : (j==2) ? a[i].z : a[i].w;
          const float cf = aj * cmm;
          acc[i][0] = fmaf(cf, xv.x, acc[i][0]);
          acc[i][1] = fmaf(cf, xv.y, acc[i][1]);
          acc[i][2] = fmaf(cf, xv.z, acc[i][2]);
          acc[i][3] = fmaf(cf, xv.w, acc[i][3]);
        }
      }
    }
#pragma unroll
    for (int i = 0; i < R; ++i) {
      const int r = rg*R + i;
      const int rr = IND ? s_inv[r] : r;
      const float4 xv = *(const float4*)(bufX + rr*SX + c0);
      const float dr = s_dis[r], sc = s_sc2[r];
      float4 v;
      v.x = fmaf(sc, xv.x, acc[i][0]*dr);
      v.y = fmaf(sc, xv.y, acc[i][1]*dr);
      v.z = fmaf(sc, xv.z, acc[i][2]*dr);
      v.w = fmaf(sc, xv.w, acc[i][3]*dr);
      *(float4*)(bufY + r*K + c0) = v;
    }
  }
  __syncthreads();
  // P3: out = relu(y @ W + b) -> bufX; fused v1 = out.Wn, v2 = out.Wr
  if constexpr (K != HH) {
    // ---- stage 1 (K=64): duplicate-free f2 layout, no k-split
    constexpr int R = M / 4;          // 8 rows per thread
    const int cg = t & 63;            // 64 f2 col-groups -> 128 cols, all lanes distinct
    const int rg = t >> 6;            // wave id == row group
    float acc0[R], acc1[R];
#pragma unroll
    for (int i = 0; i < R; ++i) { acc0[i]=0.f; acc1[i]=0.f; }
#pragma unroll 2
    for (int k0 = 0; k0 < K; k0 += 4) {
      float4 yv[R];
#pragma unroll
      for (int i = 0; i < R; ++i)     // broadcast (wave-uniform addr)
        yv[i] = *(const float4*)(bufY + (rg*R + i)*K + k0);
#pragma unroll
      for (int j = 0; j < 4; ++j) {
        const float2 w = *(const float2*)(Wg + (size_t)(k0+j)*HH + cg*2);
#pragma unroll
        for (int i = 0; i < R; ++i) {
          const float yj = (j==0) ? yv[i].x : (j==1) ? yv[i].y : (j==2) ? yv[i].z : yv[i].w;
          acc0[i] = fmaf(yj, w.x, acc0[i]);
          acc1[i] = fmaf(yj, w.y, acc1[i]);
        }
      }
    }
    const float2 b2  = *(const float2*)(bg + cg*2);
    const float2 wn2 = *(const float2*)(Wn + cg*2);
    const float2 wr2 = *(const float2*)(Wr + cg*2);
#pragma unroll
    for (int i = 0; i < R; ++i) {
      const int row = rg*R + i;
      const float ox = fmaxf(acc0[i] + b2.x, 0.f);
      const float oy = fmaxf(acc1[i] + b2.y, 0.f);
      float2 v; v.x=ox; v.y=oy;
      *(float2*)(bufX + row*HH + cg*2) = v;
      float p1 = ox*wn2.x + oy*wn2.y;
      float p2 = ox*wr2.x + oy*wr2.y;
#pragma unroll
      for (int off = 32; off >= 1; off >>= 1) {
        p1 += __shfl_xor(p1, off);
        p2 += __shfl_xor(p2, off);
      }
      if ((t & 63) == 0) { s_v1[row] = p1; s_v2[row] = p2; }
    }
  } else {
    // ---- stages 2/3 (K=128): k-split across wave-pairs + partial reduce
    constexpr int R = M / 2;          // rows per thread (8 / 4)
    const int cg  = t & 63;           // 64 f2 col-groups, all lanes distinct
    const int sub = (t >> 6) & 1;     // row half within pair
    const int pr  = t >> 7;           // k half (pair id)
    const int kbase = pr * (K/2);
    float acc0[R], acc1[R];
#pragma unroll
    for (int i = 0; i < R; ++i) { acc0[i]=0.f; acc1[i]=0.f; }
#pragma unroll 2
    for (int k0 = 0; k0 < K/2; k0 += 4) {
      float4 yv[R];
#pragma unroll
      for (int i = 0; i < R; ++i)     // broadcast (wave-uniform addr)
        yv[i] = *(const float4*)(bufY + (sub*R + i)*K + kbase + k0);
#pragma unroll
      for (int j = 0; j < 4; ++j) {
        const float2 w = *(const float2*)(Wg + (size_t)(kbase+k0+j)*HH + cg*2);
#pragma unroll
        for (int i = 0; i < R; ++i) {
          const float yj = (j==0) ? yv[i].x : (j==1) ? yv[i].y : (j==2) ? yv[i].z : yv[i].w;
          acc0[i] = fmaf(yj, w.x, acc0[i]);
          acc1[i] = fmaf(yj, w.y, acc1[i]);
        }
      }
    }
    __syncthreads();                  // all y reads done
    float* pdst = pr ? bufY : bufX;   // wave-uniform select
#pragma unroll
    for (int i = 0; i < R; ++i) {
      float2 v; v.x=acc0[i]; v.y=acc1[i];
      *(float2*)(pdst + (sub*R + i)*HH + cg*2) = v;
    }
    __syncthreads();
    // epilogue: sum partials + bias + relu + v1/v2
    constexpr int RE = M / 8;
    const int ecg = t & 31, erg = t >> 5;
    const int f0 = ecg * 4;
    const float4 b4  = *(const float4*)(bg + f0);
    const float4 wn4 = *(const float4*)(Wn + f0);
    const float4 wr4 = *(const float4*)(Wr + f0);
#pragma unroll
    for (int i = 0; i < RE; ++i) {
      const int row = erg*RE + i;
      const float4 p0 = *(const float4*)(bufX + row*HH + f0);
      const float4 p1v = *(const float4*)(bufY + row*HH + f0);
      const float ox = fmaxf(p0.x + p1v.x + b4.x, 0.f);
      const float oy = fmaxf(p0.y + p1v.y + b4.y, 0.f);
      const float oz = fmaxf(p0.z + p1v.z + b4.z, 0.f);
      const float ow = fmaxf(p0.w + p1v.w + b4.w, 0.f);
      float4 v; v.x=ox; v.y=oy; v.z=oz; v.w=ow;
      *(float4*)(bufX + row*HH + f0) = v;
      float p1 = ox*wn4.x + oy*wn4.y + oz*wn4.z + ow*wn4.w;
      float p2 = ox*wr4.x + oy*wr4.y + oz*wr4.z + ow*wr4.w;
#pragma unroll
      for (int off = 16; off >= 1; off >>= 1) {
        p1 += __shfl_xor(p1, off);
        p2 += __shfl_xor(p2, off);
      }
      if ((t & 31) == 0) { s_v1[row] = p1; s_v2[row] = p2; }
    }
  }
  __syncthreads();
  // P4: score = tanh(A_raw @ v1 + v2 + bs)
  if (t < M) {
    float sc = bs[0] + s_v2[t];
    for (int m = 0; m < M; ++m) sc += s_A[t*APAD + m] * s_v1[m];
    s_score[t] = tanhf(sc);
  }
  __syncthreads();
  // P5: rank (jax.lax.top_k order, ties -> lower index) + inverse perm
  if (t < M) {
    const float st = s_score[t]; int r = 0;
    for (int m = 0; m < M; ++m) {
      const float sm = s_score[m];
      r += (sm > st) || (sm == st && m < t);
    }
    s_rank[t] = r;
    if (r < KK) s_inv[r] = t;
  }
  __syncthreads();
  // P6: readout (gmp || gap) over gated kept rows; edge remap
  {
    const int f = t & 127, which = t >> 7;
    float acc = which ? 0.f : -INFINITY;
#pragma unroll
    for (int r = 0; r < KK; ++r) {
      const int n = s_inv[r];
      const float v = bufX[n*HH + f] * s_score[n];
      acc = which ? (acc + v) : fmaxf(acc, v);
    }
    featg[which*HH + f] = which ? acc * (1.f/KK) : acc;
  }
  if (!LAST && t < EE0) {
    const int a = s_rank[s_src[t]], b = s_rank[s_dst[t]];
    const bool val = (a < KK) && (b < KK);
    s_ew[t]  = val ? s_ew[t] : 0.f;
    s_src[t] = val ? a : 0;
    s_dst[t] = val ? b : 0;
  }
  __syncthreads();
}

__global__ __launch_bounds__(256, 5) void graph_kernel(
    const float* __restrict__ x,
    const int* __restrict__ esrc, const int* __restrict__ edst, const float* __restrict__ ewg,
    const float* __restrict__ W1, const float* __restrict__ b1,
    const float* __restrict__ Ws1r, const float* __restrict__ Ws1n, const float* __restrict__ bs1,
    const float* __restrict__ W2, const float* __restrict__ b2,
    const float* __restrict__ Ws2r, const float* __restrict__ Ws2n, const float* __restrict__ bs2,
    const float* __restrict__ W3, const float* __restrict__ b3,
    const float* __restrict__ Ws3r, const float* __restrict__ Ws3n, const float* __restrict__ bs3,
    float* __restrict__ feat)
{
  __shared__ __align__(16) float bufX[NN0*HH];   // x̂ / GCN out / partial-lo
  __shared__ __align__(16) float bufY[2048];     // y = B@x̂ / partial-hi
  __shared__ __align__(16) float s_A[NN0*APAD];  // raw adjacency
  __shared__ float s_dis[NN0], s_cm[NN0], s_sc2[NN0];
  __shared__ float s_v1[NN0], s_v2[NN0], s_score[NN0], s_ew[EE0];
  __shared__ int   s_rank[NN0], s_inv[NN0], s_src[EE0], s_dst[EE0];

  const int t = threadIdx.x;
  const int g = blockIdx.x;

  for (int idx = t; idx < NN0*NFF; idx += 256)
    bufX[idx] = x[(size_t)g*NN0*NFF + idx];     // packed stride 64
  if (t < EE0) {
    const int e = g*EE0 + t;
    s_src[t] = esrc[e] - g*NN0;
    s_dst[t] = edst[e] - g*NN0;
    s_ew[t]  = ewg[e];
  }
  __syncthreads();

  float* featg = feat + (size_t)g * SIXH;

  stage<NN0, 16, NFF, NFF, false, false>(W1, b1, Ws1r, Ws1n, bs1,
      bufX, bufY, s_A, s_dis, s_cm, s_sc2, s_v1, s_v2, s_score, s_rank, s_inv,
      s_src, s_dst, s_ew, featg, t);
  stage<16, 8, HH, HH, true, false>(W2, b2, Ws2r, Ws2n, bs2,
      bufX, bufY, s_A, s_dis, s_cm, s_sc2, s_v1, s_v2, s_score, s_rank, s_inv,
      s_src, s_dst, s_ew, featg + 256, t);
  stage<8, 4, HH, HH, true, true>(W3, b3, Ws3r, Ws3n, bs3,
      bufX, bufY, s_A, s_dis, s_cm, s_sc2, s_v1, s_v2, s_score, s_rank, s_inv,
      s_src, s_dst, s_ew, featg + 512, t);
}

// ============================================================
// DDI stage
// ============================================================

__global__ void k_deg_init(float* __restrict__ degf) {
  int i = blockIdx.x*256 + threadIdx.x;
  if (i < GG) degf[i] = 1.f;
}

__global__ void k_deg_acc(const int* __restrict__ ddi, float* __restrict__ degf) {
  int e = blockIdx.x*256 + threadIdx.x;
  if (e < E2B) atomicAdd(&degf[ddi[E2B + e]], 1.f);
}

// hdd[G,256] = feat[G,768] @ Wd[768,256]; 8 rows/block -> 1250 blocks
__global__ __launch_bounds__(256) void k_ddi_gemm(const float* __restrict__ feat,
    const float* __restrict__ Wd, float* __restrict__ hdd)
{
  __shared__ __align__(16) float s_f[8*SIXH];
  const int t = threadIdx.x;
  const int r0 = blockIdx.x * 8;
  const int cg = t & 63, rg = t >> 6;    // 4 cols x 2 rows per thread
  for (int idx = t; idx < 8*SIXH; idx += 256)
    s_f[idx] = feat[(size_t)r0*SIXH + idx];
  __syncthreads();
  float acc[2][4];
#pragma unroll
  for (int i = 0; i < 2; ++i) { acc[i][0]=0.f; acc[i][1]=0.f; acc[i][2]=0.f; acc[i][3]=0.f; }
#pragma unroll 4
  for (int k = 0; k < SIXH; ++k) {
    const float4 w = *(const float4*)(Wd + (size_t)k*DD + cg*4);
#pragma unroll
    for (int i = 0; i < 2; ++i) {
      const float a = s_f[(rg*2 + i)*SIXH + k];   // broadcast
      acc[i][0]=fmaf(a,w.x,acc[i][0]); acc[i][1]=fmaf(a,w.y,acc[i][1]);
      acc[i][2]=fmaf(a,w.z,acc[i][2]); acc[i][3]=fmaf(a,w.w,acc[i][3]);
    }
  }
#pragma unroll
  for (int i = 0; i < 2; ++i) {
    float4 v; v.x=acc[i][0]; v.y=acc[i][1]; v.z=acc[i][2]; v.w=acc[i][3];
    *(float4*)(hdd + (size_t)(r0 + rg*2 + i)*DD + cg*4) = v;
  }
}

__global__ void k_z_init(const float* __restrict__ hdd, const float* __restrict__ degf,
                         const float* __restrict__ bd, float* __restrict__ z)
{
  int idx = blockIdx.x*256 + threadIdx.x;
  if (idx < GG*DD) {
    int g = idx >> 8, f = idx & 255;
    z[idx] = hdd[idx] / degf[g] + bd[f];
  }
}

// 4 edges per block
__global__ void k_scatter(const int* __restrict__ ddi, const float* __restrict__ degf,
                          const float* __restrict__ hdd, float* __restrict__ z)
{
  const int t = threadIdx.x;
#pragma unroll
  for (int j = 0; j < 4; ++j) {
    const int e = blockIdx.x*4 + j;
    const int s = ddi[e], d = ddi[E2B + e];
    const float nrm = rsqrtf(degf[s]) * rsqrtf(degf[d]);
    atomicAdd(&z[(size_t)d*DD + t], nrm * hdd[(size_t)s*DD + t]);
  }
}

// link-prediction heads + row norms; 8 edges per block -> 1024 blocks
__global__ __launch_bounds__(256) void k_final(const float* __restrict__ z,
    const int* __restrict__ ddi, const float* __restrict__ attr,
    const float* __restrict__ Wl1, const float* __restrict__ bl1,
    const float* __restrict__ Wl2, const float* __restrict__ bl2,
    const float* __restrict__ Wl3, const float* __restrict__ bl3,
    float* __restrict__ out)
{
  __shared__ __align__(16) float s_u[8*257];
  const int t = threadIdx.x;
  const int e0 = blockIdx.x * 8;
  float lacc[8], acc[8];

  // ---- X = sigmoid(relu(z[src]) @ Wl1 + bl1)
  for (int idx = t; idx < 8*256; idx += 256) {
    const int r = idx >> 8, k = idx & 255;
    const int src = ddi[e0 + r];
    s_u[r*257 + k] = fmaxf(z[(size_t)src*DD + k], 0.f);
  }
  __syncthreads();
#pragma unroll
  for (int r = 0; r < 8; ++r) acc[r] = bl1[t];
#pragma unroll 4
  for (int k = 0; k < 256; ++k) {
    const float w = Wl1[(size_t)k*DD + t];
#pragma unroll
    for (int r = 0; r < 8; ++r) acc[r] = fmaf(s_u[r*257 + k], w, acc[r]);
  }
#pragma unroll
  for (int r = 0; r < 8; ++r) {
    const float sx = 1.f / (1.f + expf(-acc[r]));
    lacc[r] = sx;
    const int e = e0 + r;
    if (e < BB) out[12288 + (size_t)e*DD + t] = sx;
  }
  __syncthreads();

  // ---- Y = sigmoid(relu(z[dst]) @ Wl2 + bl2)
  for (int idx = t; idx < 8*256; idx += 256) {
    const int r = idx >> 8, k = idx & 255;
    const int dst = ddi[E2B + e0 + r];
    s_u[r*257 + k] = fmaxf(z[(size_t)dst*DD + k], 0.f);
  }
  __syncthreads();
#pragma unroll
  for (int r = 0; r < 8; ++r) acc[r] = bl2[t];
#pragma unroll 4
  for (int k = 0; k < 256; ++k) {
    const float w = Wl2[(size_t)k*DD + t];
#pragma unroll
    for (int r = 0; r < 8; ++r) acc[r] = fmaf(s_u[r*257 + k], w, acc[r]);
  }
#pragma unroll
  for (int r = 0; r < 8; ++r) lacc[r] -= 1.f / (1.f + expf(-acc[r]));
  __syncthreads();

  // ---- A = sigmoid(attr @ Wl3 + bl3)
  for (int idx = t; idx < 8*64; idx += 256) {
    const int r = idx >> 6, k = idx & 63;
    s_u[r*257 + k] = attr[(size_t)(e0 + r)*NFF + k];
  }
  __syncthreads();
#pragma unroll
  for (int r = 0; r < 8; ++r) acc[r] = bl3[t];
#pragma unroll 4
  for (int k = 0; k < 64; ++k) {
    const float w = Wl3[(size_t)k*DD + t];
#pragma unroll
    for (int r = 0; r < 8; ++r) acc[r] = fmaf(s_u[r*257 + k], w, acc[r]);
  }
#pragma unroll
  for (int r = 0; r < 8; ++r) lacc[r] += 1.f / (1.f + expf(-acc[r]));
  __syncthreads();

  // ---- squared residual, 32-lane row reduce
#pragma unroll
  for (int r = 0; r < 8; ++r) s_u[r*257 + t] = lacc[r]*lacc[r];
  __syncthreads();
  {
    const int row = t >> 5, l = t & 31;
    float s = 0.f;
#pragma unroll
    for (int j = 0; j < 8; ++j) s += s_u[row*257 + l + 32*j];
#pragma unroll
    for (int off = 16; off >= 1; off >>= 1) s += __shfl_xor(s, off);
    if (l == 0) {
      const float nrm = sqrtf(s);
      const int e = e0 + row;
      if (e < BB) out[4096 + e] = nrm;
      else        out[8192 + (e - BB)] = nrm;
    }
  }
}

__global__ void k_loss(float* __restrict__ out) {
  int i = blockIdx.x*256 + threadIdx.x;
  if (i < BB) out[i] = 2.f*(float)DD - out[4096 + i] + 0.5f*out[8192 + i];
}

// ============================================================

extern "C" void kernel_launch(void* const* d_in, const int* in_sizes, int n_in,
                              void* d_out, int out_size, void* d_ws, size_t ws_size,
                              hipStream_t stream)
{
  const float* x    = (const float*)d_in[0];
  const int*   esrc = (const int*)d_in[1];
  const int*   edst = (const int*)d_in[2];
  const float* ewt  = (const float*)d_in[3];
  const int*   ddi  = (const int*)d_in[4];
  const float* attr = (const float*)d_in[5];
  const float* W1   = (const float*)d_in[6];  const float* b1  = (const float*)d_in[7];
  const float* Ws1r = (const float*)d_in[8];  const float* Ws1n= (const float*)d_in[9];  const float* bs1 = (const float*)d_in[10];
  const float* W2   = (const float*)d_in[11]; const float* b2  = (const float*)d_in[12];
  const float* Ws2r = (const float*)d_in[13]; const float* Ws2n= (const float*)d_in[14]; const float* bs2 = (const float*)d_in[15];
  const float* W3   = (const float*)d_in[16]; const float* b3  = (const float*)d_in[17];
  const float* Ws3r = (const float*)d_in[18]; const float* Ws3n= (const float*)d_in[19]; const float* bs3 = (const float*)d_in[20];
  const float* Wd   = (const float*)d_in[21]; const float* bd  = (const float*)d_in[22];
  const float* Wl1  = (const float*)d_in[23]; const float* bl1 = (const float*)d_in[24];
  const float* Wl2  = (const float*)d_in[25]; const float* bl2 = (const float*)d_in[26];
  const float* Wl3  = (const float*)d_in[27]; const float* bl3 = (const float*)d_in[28];

  float* ws   = (float*)d_ws;
  float* feat = ws;
  float* hdd  = feat + (size_t)GG*SIXH;
  float* zb   = hdd  + (size_t)GG*DD;
  float* degf = zb   + (size_t)GG*DD;
  float* out  = (float*)d_out;

  graph_kernel<<<GG, 256, 0, stream>>>(x, esrc, edst, ewt,
      W1, b1, Ws1r, Ws1n, bs1, W2, b2, Ws2r, Ws2n, bs2, W3, b3, Ws3r, Ws3n, bs3, feat);
  k_deg_init<<<(GG + 255)/256, 256, 0, stream>>>(degf);
  k_deg_acc<<<(E2B + 255)/256, 256, 0, stream>>>(ddi, degf);
  k_ddi_gemm<<<GG/8, 256, 0, stream>>>(feat, Wd, hdd);
  k_z_init<<<(GG*DD + 255)/256, 256, 0, stream>>>(hdd, degf, bd, zb);
  k_scatter<<<E2B/4, 256, 0, stream>>>(ddi, degf, hdd, zb);
  k_final<<<E2B/8, 256, 0, stream>>>(zb, ddi, attr, Wl1, bl1, Wl2, bl2, Wl3, bl3, out);
  k_loss<<<(BB + 255)/256, 256, 0, stream>>>(out);
}